// Round 1
// baseline (107.065 us; speedup 1.0000x reference)
//
#include <hip/hip_runtime.h>

#define LNUM 12
#define TNUM 12
#define NPASS 7   // 1 initial pass + HORIZON=6

// Each thread owns one (b,n) scalar-GRU chain. All state in registers.
__global__ __launch_bounds__(256, 1)
void gru_chain_kernel(const float* __restrict__ x,
                      const float* __restrict__ w_ih,
                      const float* __restrict__ w_hh,
                      const float* __restrict__ b_ih,
                      const float* __restrict__ b_hh,
                      float* __restrict__ out,
                      int total) {
    const int tid = blockIdx.x * blockDim.x + threadIdx.x;
    if (tid >= total) return;

    const float NL2E = -1.4426950408889634f; // -log2(e): sigmoid via exp2
    const float TL2E =  2.8853900817779268f; //  2*log2(e): tanh via exp2

    // Pre-scaled weights, fully static-indexed -> registers.
    // Gates 0,1 (r,z): scale by -log2(e), fuse b_ih+b_hh.
    // Gate 2 (n): scale by 2*log2(e); keep gi2/gh2 biases separate (r multiplies gh2 only).
    float wi0[LNUM], wi1[LNUM], wi2[LNUM];
    float wh0[LNUM], wh1[LNUM], wh2[LNUM];
    float b0[LNUM], b1[LNUM], bi2[LNUM], bh2[LNUM];
#pragma unroll
    for (int l = 0; l < LNUM; ++l) {
        wi0[l] = NL2E * w_ih[l*3+0];
        wi1[l] = NL2E * w_ih[l*3+1];
        wi2[l] = TL2E * w_ih[l*3+2];
        wh0[l] = NL2E * w_hh[l*3+0];
        wh1[l] = NL2E * w_hh[l*3+1];
        wh2[l] = TL2E * w_hh[l*3+2];
        b0[l]  = NL2E * (b_ih[l*3+0] + b_hh[l*3+0]);
        b1[l]  = NL2E * (b_ih[l*3+1] + b_hh[l*3+1]);
        bi2[l] = TL2E * b_ih[l*3+2];
        bh2[l] = TL2E * b_hh[l*3+2];
    }

    // Load this chain's 12 inputs (contiguous, 48B -> 3x float4).
    float seq[TNUM];
    const float4* xv = reinterpret_cast<const float4*>(x + (size_t)tid * TNUM);
#pragma unroll
    for (int i = 0; i < TNUM / 4; ++i) {
        float4 v = xv[i];
        seq[i*4+0] = v.x; seq[i*4+1] = v.y; seq[i*4+2] = v.z; seq[i*4+3] = v.w;
    }

    float h[LNUM];
#pragma unroll
    for (int l = 0; l < LNUM; ++l) h[l] = 0.0f;

#pragma unroll 1   // keep pass loop rolled: bounds code size; regs persist
    for (int p = 0; p < NPASS; ++p) {
#pragma unroll     // t fully unrolled -> seq[t] stays in registers
        for (int t = 0; t < TNUM; ++t) {
            float inp = seq[t];
#pragma unroll
            for (int l = 0; l < LNUM; ++l) {
                // pre-scaled gate pre-activations
                float ar  = fmaf(inp, wi0[l], fmaf(h[l], wh0[l], b0[l])); // -log2e*(gi0+gh0)
                float az  = fmaf(inp, wi1[l], fmaf(h[l], wh1[l], b1[l])); // -log2e*(gi1+gh1)
                float gi2 = fmaf(inp,  wi2[l], bi2[l]);                   // 2log2e*gi2
                float gh2 = fmaf(h[l], wh2[l], bh2[l]);                   // 2log2e*gh2

                float er = __builtin_amdgcn_exp2f(ar);       // exp(-(gi0+gh0))
                float ez = __builtin_amdgcn_exp2f(az);
                float r  = __builtin_amdgcn_rcpf(1.0f + er); // sigmoid
                float z  = __builtin_amdgcn_rcpf(1.0f + ez);

                float an = fmaf(r, gh2, gi2);                // 2log2e*(gi2 + r*gh2)
                float en = __builtin_amdgcn_exp2f(an);       // exp(2p)
                float u  = __builtin_amdgcn_rcpf(1.0f + en);
                float n  = fmaf(-2.0f, u, 1.0f);             // tanh(p)

                float hn = fmaf(z, h[l] - n, n);             // (1-z)*n + z*h
                h[l] = hn;
                inp  = hn;                                    // feeds next layer
            }
            seq[t] = inp;  // top-layer output becomes next pass's input at step t
        }
    }

    // out[l, b, 0, n, 0] -> flat l*total + tid ; coalesced across lanes
#pragma unroll
    for (int l = 0; l < LNUM; ++l) {
        out[(size_t)l * total + tid] = h[l];
    }
}

extern "C" void kernel_launch(void* const* d_in, const int* in_sizes, int n_in,
                              void* d_out, int out_size, void* d_ws, size_t ws_size,
                              hipStream_t stream) {
    const float* x    = (const float*)d_in[0];
    const float* w_ih = (const float*)d_in[1];
    const float* w_hh = (const float*)d_in[2];
    const float* b_ih = (const float*)d_in[3];
    const float* b_hh = (const float*)d_in[4];
    float* out = (float*)d_out;

    const int total = in_sizes[0] / TNUM;   // B*N = 65536
    const int block = 256;
    const int grid  = (total + block - 1) / block;
    gru_chain_kernel<<<grid, block, 0, stream>>>(x, w_ih, w_hh, b_ih, b_hh, out, total);
}